// Round 1
// baseline (553.486 us; speedup 1.0000x reference)
//
#include <hip/hip_runtime.h>
#include <math.h>

// AutoLUT forward, MI355X. B=4, N=512, K=3 (PAD=2), Q=16, L=17, UPSCALE=4, SAMPLERS=3.
static constexpr int B_ = 4;
static constexpr int N_ = 512;
static constexpr int N4_ = 2048;
static constexpr int LUT_ROWS = 83521;         // 17^4
static constexpr int ST0 = 4913, ST1 = 289, ST2 = 17, ST3 = 1;

__device__ __forceinline__ float fixw(float v) {
    v = rintf(v * 127.0f);
    return fminf(fmaxf(v, -127.0f), 127.0f);
}

__global__ void fix_lut_kernel(const float* __restrict__ in, float* __restrict__ out, int n) {
    int idx = blockIdx.x * blockDim.x + threadIdx.x;
    int gsz = gridDim.x * blockDim.x;
    for (int t = idx; t < n; t += gsz) out[t] = fixw(in[t]);
}

struct Simplex {
    int v0, v1, v2, v3, v4;
    float w0, w1, w2, w3, w4;
};

// 4-D simplex lookup setup. floor/mod by 16 are exact in fp32 (pow-2); sort is a
// stable descending bubble network (ties -> zero-weight vertices, order-irrelevant).
__device__ __forceinline__ Simplex simplex4(float a, float b, float c, float d) {
    float fl0 = floorf(a * 0.0625f), fl1 = floorf(b * 0.0625f),
          fl2 = floorf(c * 0.0625f), fl3 = floorf(d * 0.0625f);
    float f[4] = { a - 16.0f * fl0, b - 16.0f * fl1, c - 16.0f * fl2, d - 16.0f * fl3 };
    int l0 = min(max((int)fl0, 0), 15);
    int l1 = min(max((int)fl1, 0), 15);
    int l2 = min(max((int)fl2, 0), 15);
    int l3 = min(max((int)fl3, 0), 15);
    int st[4] = { ST0, ST1, ST2, ST3 };
#define CSW(A, Bq) { if (f[A] < f[Bq]) { float tf = f[A]; f[A] = f[Bq]; f[Bq] = tf; \
                                         int ts = st[A]; st[A] = st[Bq]; st[Bq] = ts; } }
    CSW(0, 1) CSW(1, 2) CSW(2, 3) CSW(0, 1) CSW(1, 2) CSW(0, 1)
#undef CSW
    Simplex s;
    s.v0 = l0 * ST0 + l1 * ST1 + l2 * ST2 + l3;
    s.v1 = s.v0 + st[0];
    s.v2 = s.v1 + st[1];
    s.v3 = s.v2 + st[2];
    s.v4 = s.v3 + st[3];
    s.w0 = 16.0f - f[0];
    s.w1 = f[0] - f[1];
    s.w2 = f[1] - f[2];
    s.w3 = f[2] - f[3];
    s.w4 = f[3];
    return s;
}

// Per-rotation tap remap: rotation r + pad-bottom/right(edge) + VALID conv +
// rotate-back collapses to clamped neighborhood reads in the original frame.
__device__ __forceinline__ void tapmap(int r, int di, int dj, int& pa, int& pb) {
    if (r == 0)      { pa = 2 + di; pb = 2 + dj; }
    else if (r == 1) { pa = 2 + dj; pb = 2 - di; }
    else if (r == 2) { pa = 2 - di; pb = 2 - dj; }
    else             { pa = 2 - dj; pb = 2 + di; }
}

template <bool PF>
__global__ __launch_bounds__(256) void stage0_kernel(
    const float* __restrict__ x,       // (4,512,512), [0,1]
    const float* __restrict__ lut0,    // (3,83521) fixed (or raw if !PF)
    const float* __restrict__ samp0,   // (3,4,3,3)
    const float* __restrict__ sbias0,  // (3,4)
    float* __restrict__ x1)            // out: (4,512,512), integer-valued 0..255
{
    int tid = blockIdx.x * blockDim.x + threadIdx.x;
    if (tid >= B_ * N_ * N_) return;
    int j = tid & (N_ - 1);
    int i = (tid >> 9) & (N_ - 1);
    int b = tid >> 18;

    float nb[5][5];
    const float* xb = x + (size_t)b * N_ * N_;
    #pragma unroll
    for (int a = 0; a < 5; ++a) {
        int ri = min(max(i - 2 + a, 0), N_ - 1);
        #pragma unroll
        for (int c = 0; c < 5; ++c) {
            int ci = min(max(j - 2 + c, 0), N_ - 1);
            nb[a][c] = xb[ri * N_ + ci] * 255.0f;
        }
    }

    float pred = 0.0f;
    for (int s = 0; s < 3; ++s) {
        const float* w  = samp0 + s * 36;
        const float* sb = sbias0 + s * 4;
        const float* lut = lut0 + (size_t)s * LUT_ROWS;
        float acc = 0.0f;
        #pragma unroll
        for (int r = 0; r < 4; ++r) {
            float vals[4];
            #pragma unroll
            for (int ch = 0; ch < 4; ++ch) {
                float v = 0.0f;
                #pragma unroll
                for (int di = 0; di < 3; ++di)
                    #pragma unroll
                    for (int dj = 0; dj < 3; ++dj) {
                        int pa, pb;
                        tapmap(r, di, dj, pa, pb);
                        v += w[ch * 9 + di * 3 + dj] * nb[pa][pb];
                    }
                vals[ch] = v + sb[ch];
            }
            Simplex sx = simplex4(vals[0], vals[1], vals[2], vals[3]);
            float p0 = lut[sx.v0], p1 = lut[sx.v1], p2 = lut[sx.v2],
                  p3 = lut[sx.v3], p4 = lut[sx.v4];
            if (!PF) { p0 = fixw(p0); p1 = fixw(p1); p2 = fixw(p2); p3 = fixw(p3); p4 = fixw(p4); }
            float o = (sx.w0 * p0 + sx.w1 * p1 + sx.w2 * p2 + sx.w3 * p3 + sx.w4 * p4) * 0.0625f;
            acc = rintf(acc + o);   // ste_round after each rotation
        }
        pred += acc;
    }
    x1[tid] = rintf(fminf(fmaxf(pred / 12.0f + 127.0f, 0.0f), 255.0f));
}

template <bool PF>
__global__ __launch_bounds__(256) void stage1_kernel(
    const float* __restrict__ x,       // original (4,512,512), [0,1]
    const float* __restrict__ x1,      // stage-0 out, 0..255
    const float* __restrict__ lut1,    // (3,83521,16) fixed (or raw if !PF)
    const float* __restrict__ samp1,   // (3,4,3,3)
    const float* __restrict__ sbias1,  // (3,4)
    const float* __restrict__ resw1,   // (3,2,2)
    float* __restrict__ out)           // (4,2048,2048)
{
    int tid = blockIdx.x * blockDim.x + threadIdx.x;
    if (tid >= B_ * N_ * N_) return;
    int j = tid & (N_ - 1);
    int i = (tid >> 9) & (N_ - 1);
    int b = tid >> 18;

    float nc[5][5], np[5][5];
    const float* xb  = x  + (size_t)b * N_ * N_;
    const float* x1b = x1 + (size_t)b * N_ * N_;
    #pragma unroll
    for (int a = 0; a < 5; ++a) {
        int ri = min(max(i - 2 + a, 0), N_ - 1);
        #pragma unroll
        for (int c = 0; c < 5; ++c) {
            int ci = min(max(j - 2 + c, 0), N_ - 1);
            nc[a][c] = x1b[ri * N_ + ci];
            np[a][c] = xb[ri * N_ + ci] * 255.0f;
        }
    }

    float tot[16];
    #pragma unroll
    for (int k = 0; k < 16; ++k) tot[k] = 0.0f;

    for (int s = 0; s < 3; ++s) {
        const float* w  = samp1 + s * 36;
        const float* sb = sbias1 + s * 4;
        const float* lut = lut1 + (size_t)s * LUT_ROWS * 16;
        float rw[4];
        #pragma unroll
        for (int ch = 0; ch < 4; ++ch)
            rw[ch] = fminf(fmaxf(resw1[s * 4 + ch], 0.0f), 1.0f);

        float acc[16];
        #pragma unroll
        for (int k = 0; k < 16; ++k) acc[k] = 0.0f;

        #pragma unroll
        for (int r = 0; r < 4; ++r) {
            float vals[4];
            #pragma unroll
            for (int ch = 0; ch < 4; ++ch) {
                float vc = 0.0f, vp = 0.0f;
                #pragma unroll
                for (int di = 0; di < 3; ++di)
                    #pragma unroll
                    for (int dj = 0; dj < 3; ++dj) {
                        int pa, pb;
                        tapmap(r, di, dj, pa, pb);
                        float wt = w[ch * 9 + di * 3 + dj];
                        vc += wt * nc[pa][pb];
                        vp += wt * np[pa][pb];
                    }
                vc += sb[ch];
                vp += sb[ch];
                vals[ch] = rw[ch] * vp + (1.0f - rw[ch]) * vc;   // residual blend
            }
            Simplex sx = simplex4(vals[0], vals[1], vals[2], vals[3]);
            const float* r0 = lut + (size_t)sx.v0 * 16;
            const float* r1 = lut + (size_t)sx.v1 * 16;
            const float* r2 = lut + (size_t)sx.v2 * 16;
            const float* r3 = lut + (size_t)sx.v3 * 16;
            const float* r4 = lut + (size_t)sx.v4 * 16;
            float oc[16];
            #pragma unroll
            for (int k = 0; k < 16; ++k) {
                float p0 = r0[k], p1 = r1[k], p2 = r2[k], p3 = r3[k], p4 = r4[k];
                if (!PF) { p0 = fixw(p0); p1 = fixw(p1); p2 = fixw(p2); p3 = fixw(p3); p4 = fixw(p4); }
                oc[k] = (sx.w0 * p0 + sx.w1 * p1 + sx.w2 * p2 + sx.w3 * p3 + sx.w4 * p4) * 0.0625f;
            }
            // scatter rotated 4x4 sub-block into the original-orientation accumulator
            #pragma unroll
            for (int u = 0; u < 4; ++u)
                #pragma unroll
                for (int v = 0; v < 4; ++v) {
                    int k = 4 * u + v;
                    int c = (r == 0) ? (4 * u + v)
                          : (r == 1) ? (4 * (3 - v) + u)
                          : (r == 2) ? (4 * (3 - u) + (3 - v))
                                     : (4 * v + (3 - u));
                    acc[k] = rintf(acc[k] + oc[c]);   // ste_round after each rotation
                }
        }
        #pragma unroll
        for (int k = 0; k < 16; ++k) tot[k] += acc[k];
    }

    float* ob = out + (size_t)b * N4_ * N4_ + (size_t)(i * 4) * N4_ + (j * 4);
    #pragma unroll
    for (int u = 0; u < 4; ++u)
        #pragma unroll
        for (int v = 0; v < 4; ++v) {
            float val = rintf(fminf(fmaxf(tot[4 * u + v] / 3.0f, 0.0f), 255.0f)) / 255.0f;
            ob[u * N4_ + v] = val;
        }
}

extern "C" void kernel_launch(void* const* d_in, const int* in_sizes, int n_in,
                              void* d_out, int out_size, void* d_ws, size_t ws_size,
                              hipStream_t stream) {
    const float* x      = (const float*)d_in[0];
    const float* lut0   = (const float*)d_in[1];
    const float* lut1   = (const float*)d_in[2];
    const float* samp0  = (const float*)d_in[3];
    const float* samp1  = (const float*)d_in[4];
    const float* sbias0 = (const float*)d_in[5];
    const float* sbias1 = (const float*)d_in[6];
    const float* resw1  = (const float*)d_in[7];
    float* out = (float*)d_out;
    float* ws  = (float*)d_ws;

    const size_t N_X1 = (size_t)B_ * N_ * N_;       // 1,048,576 floats
    const size_t N_L0 = (size_t)3 * LUT_ROWS;       // 250,563
    const size_t N_L1 = (size_t)3 * LUT_ROWS * 16;  // 4,009,008
    size_t off_x1 = 0;
    size_t off_l0 = N_X1;                           // 4 MB offset, 16B-aligned
    size_t off_l1 = (off_l0 + N_L0 + 3) & ~(size_t)3;
    size_t need_bytes = (off_l1 + N_L1) * sizeof(float);

    float* x1 = ws + off_x1;
    const int threads = 256;
    const int grid = (B_ * N_ * N_) / threads;      // 4096

    if (ws_size >= need_bytes) {
        float* l0f = ws + off_l0;
        float* l1f = ws + off_l1;
        fix_lut_kernel<<<1024, threads, 0, stream>>>(lut0, l0f, (int)N_L0);
        fix_lut_kernel<<<4096, threads, 0, stream>>>(lut1, l1f, (int)N_L1);
        stage0_kernel<true><<<grid, threads, 0, stream>>>(x, l0f, samp0, sbias0, x1);
        stage1_kernel<true><<<grid, threads, 0, stream>>>(x, x1, l1f, samp1, sbias1, resw1, out);
    } else {
        // ws only big enough for x1: fix LUT values on the fly at gather time.
        stage0_kernel<false><<<grid, threads, 0, stream>>>(x, lut0, samp0, sbias0, x1);
        stage1_kernel<false><<<grid, threads, 0, stream>>>(x, x1, lut1, samp1, sbias1, resw1, out);
    }
}